// Round 3
// baseline (753.368 us; speedup 1.0000x reference)
//
#include <hip/hip_runtime.h>

// EmbeddingLSQ: out[t,d] = (idx[t]==0) ? 0 : rint(clamp(W[d,idx[t]]/a,-8,7))*a
// idx[t] = position of the 1.0 in one-hot row x[t,:].
//
// 1 block (256 thr) per token.
// Phase 1: x-row scan, 2x 16B per thread per iteration (2 KB/wave in flight),
//          nontemporal loads (don't evict w from L2/L3), shared-flag early
//          exit (expected ~53% of row read).
// Phase 2: 4 independent w gathers per thread (w stays cached), fp32 LSQ
//          fake-quant, one nontemporal 16B store per thread.

typedef float v4f __attribute__((ext_vector_type(4)));  // native vector: OK for
                                                        // __builtin_nontemporal_*

constexpr int VOCAB  = 32000;
constexpr int DIM    = 1024;
constexpr int TOKENS = 4096;
constexpr int V4     = VOCAB / 4;   // 8000 x 16B per row
constexpr int BLOCK  = 256;

__global__ __launch_bounds__(BLOCK) void emb_lsq_kernel(
    const float* __restrict__ x,
    const float* __restrict__ w,
    const float* __restrict__ alpha,
    float* __restrict__ out)
{
    const int t   = blockIdx.x;
    const int tid = threadIdx.x;

    __shared__ int s_idx;
    if (tid == 0) s_idx = -1;
    __syncthreads();

    // ---- Phase 1: find the one-hot index in x[t, :] ----
    const v4f* xr = reinterpret_cast<const v4f*>(x + (size_t)t * VOCAB);
    int found = -1;
    for (int i = tid; i < V4; i += 2 * BLOCK) {
        const int i2 = i + BLOCK;
        const bool has2 = (i2 < V4);
        v4f v1 = __builtin_nontemporal_load(&xr[i]);      // both loads issued
        v4f v2 = has2 ? __builtin_nontemporal_load(&xr[i2]) : (v4f)0.f;
        if      (v1.x > 0.5f) found = 4 * i + 0;
        else if (v1.y > 0.5f) found = 4 * i + 1;
        else if (v1.z > 0.5f) found = 4 * i + 2;
        else if (v1.w > 0.5f) found = 4 * i + 3;
        if (found < 0 && has2) {
            if      (v2.x > 0.5f) found = 4 * i2 + 0;
            else if (v2.y > 0.5f) found = 4 * i2 + 1;
            else if (v2.z > 0.5f) found = 4 * i2 + 2;
            else if (v2.w > 0.5f) found = 4 * i2 + 3;
        }
        if (found >= 0) { s_idx = found; break; }          // unique finder
        if (*(volatile int*)&s_idx >= 0) break;            // early exit
    }
    __syncthreads();
    const int idx = s_idx;

    // ---- Phase 2: gather + LSQ fake-quant + 16B row write ----
    v4f* orow = reinterpret_cast<v4f*>(out + (size_t)t * DIM);
    if (idx <= 0) {                                        // PAD (or degenerate)
        v4f z = 0.f;
        __builtin_nontemporal_store(z, &orow[tid]);
    } else {
        const float a = alpha[0];
        const size_t col = (size_t)idx;
        const int d0 = 4 * tid;                            // DIM/4 == BLOCK
        float w0 = w[(size_t)(d0 + 0) * VOCAB + col];      // 4 independent
        float w1 = w[(size_t)(d0 + 1) * VOCAB + col];      // gathers in flight
        float w2 = w[(size_t)(d0 + 2) * VOCAB + col];
        float w3 = w[(size_t)(d0 + 3) * VOCAB + col];
        v4f q;
        q.x = rintf(fminf(fmaxf(w0 / a, -8.f), 7.f)) * a;
        q.y = rintf(fminf(fmaxf(w1 / a, -8.f), 7.f)) * a;
        q.z = rintf(fminf(fmaxf(w2 / a, -8.f), 7.f)) * a;
        q.w = rintf(fminf(fmaxf(w3 / a, -8.f), 7.f)) * a;
        __builtin_nontemporal_store(q, &orow[tid]);
    }
}

extern "C" void kernel_launch(void* const* d_in, const int* in_sizes, int n_in,
                              void* d_out, int out_size, void* d_ws, size_t ws_size,
                              hipStream_t stream) {
    const float* x     = (const float*)d_in[0];   // [TOKENS, VOCAB]
    const float* w     = (const float*)d_in[1];   // [DIM, VOCAB]
    const float* alpha = (const float*)d_in[2];   // [1]
    float* out         = (float*)d_out;           // [TOKENS, DIM]

    emb_lsq_kernel<<<TOKENS, BLOCK, 0, stream>>>(x, w, alpha, out);
}

// Round 4
// 719.773 us; speedup vs baseline: 1.0467x; 1.0467x over previous
//
#include <hip/hip_runtime.h>

// EmbeddingLSQ: out[t,d] = (idx[t]==0) ? 0 : rint(clamp(W[d,idx[t]]/a,-8,7))*a
// idx[t] = position of the 1.0 in one-hot row x[t,:].
//
// 1 WAVE (64 threads) per token; 4096 blocks => 4096 waves, all resident
// (device capacity 8192). Phase 1 scans the 128 KB x row 4 KB/iteration with
// a register-only ballot early-exit (no LDS flag, no __syncthreads, no
// vmcnt-drain-to-LDS per iteration). Phase 2: 16 independent w gathers per
// lane, fp32 LSQ fake-quant, 4 coalesced 16B stores per lane.

typedef float v4f __attribute__((ext_vector_type(4)));

constexpr int VOCAB  = 32000;
constexpr int DIM    = 1024;
constexpr int TOKENS = 4096;
constexpr int V4     = VOCAB / 4;       // 8000 16B chunks per row
constexpr int WAVE   = 64;
constexpr int FULL_ITERS = V4 / 256;    // 31 full 256-chunk windows
constexpr int TAIL_BASE  = FULL_ITERS * 256;  // 7936, tail = 64 chunks

__device__ __forceinline__ int check4(v4f v, int chunk) {
    if (v.x > 0.5f) return 4 * chunk + 0;
    if (v.y > 0.5f) return 4 * chunk + 1;
    if (v.z > 0.5f) return 4 * chunk + 2;
    if (v.w > 0.5f) return 4 * chunk + 3;
    return -1;
}

__global__ __launch_bounds__(WAVE) void emb_lsq_kernel(
    const float* __restrict__ x,
    const float* __restrict__ w,
    const float* __restrict__ alpha,
    float* __restrict__ out)
{
    const int t    = blockIdx.x;
    const int lane = threadIdx.x;

    // ---- Phase 1: find one-hot index; ballot early-exit ----
    const v4f* xr = reinterpret_cast<const v4f*>(x + (size_t)t * VOCAB);
    int found = -1;
    for (int k = 0; k < FULL_ITERS; ++k) {
        const int i = lane + 256 * k;
        v4f a0 = xr[i];               // 4 loads issued back-to-back:
        v4f a1 = xr[i +  64];         // 4 KB/wave in flight
        v4f a2 = xr[i + 128];
        v4f a3 = xr[i + 192];
        int f;
        if ((f = check4(a0, i      )) >= 0) found = f;
        else if ((f = check4(a1, i +  64)) >= 0) found = f;
        else if ((f = check4(a2, i + 128)) >= 0) found = f;
        else if ((f = check4(a3, i + 192)) >= 0) found = f;
        if (__ballot(found >= 0)) break;   // register-only exit check
    }
    if (!__ballot(found >= 0)) {           // tail: chunks 7936..7999
        v4f a = xr[TAIL_BASE + lane];
        found = check4(a, TAIL_BASE + lane);
    }
    unsigned long long m = __ballot(found >= 0);
    const int idx = m ? __shfl(found, (int)__ffsll(m) - 1) : -1;

    // ---- Phase 2: gather + LSQ fake-quant + coalesced 16B stores ----
    v4f* orow = reinterpret_cast<v4f*>(out + (size_t)t * DIM);
    if (idx <= 0) {                        // PAD_IDX (or degenerate) -> zeros
        v4f z = 0.f;
        #pragma unroll
        for (int j = 0; j < 4; ++j) orow[lane + 64 * j] = z;
    } else {
        const float a = alpha[0];
        const size_t col = (size_t)idx;
        float wv[16];
        #pragma unroll
        for (int j = 0; j < 4; ++j) {      // 16 independent gathers in flight
            const int d0 = 4 * lane + 256 * j;
            wv[4*j+0] = w[(size_t)(d0 + 0) * VOCAB + col];
            wv[4*j+1] = w[(size_t)(d0 + 1) * VOCAB + col];
            wv[4*j+2] = w[(size_t)(d0 + 2) * VOCAB + col];
            wv[4*j+3] = w[(size_t)(d0 + 3) * VOCAB + col];
        }
        #pragma unroll
        for (int j = 0; j < 4; ++j) {
            v4f q;
            q.x = rintf(fminf(fmaxf(wv[4*j+0] / a, -8.f), 7.f)) * a;
            q.y = rintf(fminf(fmaxf(wv[4*j+1] / a, -8.f), 7.f)) * a;
            q.z = rintf(fminf(fmaxf(wv[4*j+2] / a, -8.f), 7.f)) * a;
            q.w = rintf(fminf(fmaxf(wv[4*j+3] / a, -8.f), 7.f)) * a;
            orow[lane + 64 * j] = q;       // lanes consecutive: 1 KB/store instr
        }
    }
}

extern "C" void kernel_launch(void* const* d_in, const int* in_sizes, int n_in,
                              void* d_out, int out_size, void* d_ws, size_t ws_size,
                              hipStream_t stream) {
    const float* x     = (const float*)d_in[0];   // [TOKENS, VOCAB]
    const float* w     = (const float*)d_in[1];   // [DIM, VOCAB]
    const float* alpha = (const float*)d_in[2];   // [1]
    float* out         = (float*)d_out;           // [TOKENS, DIM]

    emb_lsq_kernel<<<TOKENS, WAVE, 0, stream>>>(x, w, alpha, out);
}